// Round 12
// baseline (309.983 us; speedup 1.0000x reference)
//
#include <hip/hip_runtime.h>

typedef __bf16 bf16x8 __attribute__((ext_vector_type(8)));
typedef float f32x4 __attribute__((ext_vector_type(4)));
typedef unsigned short u16;

#define NN 10000
#define NE 640000
#define DIM 128
#define TD 64
#define LDT2 112  // 96-col Tbuf stride (bf16 elems): temb(64) + dist(1) + zeros
#define LDX 136   // 128-col tile stride (bf16 elems)
#define LDH 136

__device__ __forceinline__ u16 f2bf(float f){
    union { float f; unsigned u; } v; v.f = f;
    unsigned r = v.u + 0x7fffu + ((v.u >> 16) & 1u);
    return (u16)(r >> 16);
}
__device__ __forceinline__ unsigned f2bf2(float a, float b){   // low=a, high=b, RNE
    unsigned r;
    asm("v_cvt_pk_bf16_f32 %0, %1, %2" : "=v"(r) : "v"(a), "v"(b));
    return r;
}
__device__ __forceinline__ float bfu2f(unsigned hs){
    union { unsigned u; float f; } v; v.u = hs << 16; return v.f;
}
__device__ __forceinline__ float silu_f(float x){ return x / (1.0f + __expf(-x)); }

// K-pair permutation: LDS phys col p = group + 2*idx + nbit  <->  orig = group + nbit*16 + idx
__device__ __forceinline__ int korig(int kp){
    return (kp & ~31) + ((kp & 1) << 4) + ((kp & 31) >> 1);
}

// ---------------- K1: weight prep + dst histogram + zero m_i/coord ----------------
__global__ __launch_bounds__(256) void k_prep1(
    const float* __restrict__ eW1, const float* __restrict__ nW1,
    const float* __restrict__ eW2, const float* __restrict__ cW1,
    const float* __restrict__ nW2, const int* __restrict__ edst,
    u16* __restrict__ nW1t, u16* __restrict__ eW2tP, u16* __restrict__ cW1t,
    u16* __restrict__ nW2t, u16* __restrict__ tWe2,
    u16* __restrict__ eW1tS, u16* __restrict__ eW1tD,
    int* __restrict__ deg, float* __restrict__ m_i, float* __restrict__ coord_out)
{
    int i = blockIdx.x * 256 + threadIdx.x;     // grid: 2500 blocks = 640000 threads
    if (i < NE) {
        atomicAdd(&deg[edst[i]], 1);
        *reinterpret_cast<float2*>(m_i + (size_t)i * 2) = make_float2(0.f, 0.f);
    }
    if (i < NN * 3) coord_out[i] = 0.f;

    if (i < 40960) {                       // nW1t [128][320]
        int j = i / 320, k = i - j * 320;
        nW1t[i] = f2bf(nW1[k * DIM + j]);
    } else if (i < 57344) {                // eW2tP [128][128], K rows pair-permuted
        int t = i - 40960; int j = t >> 7, kp = t & 127;
        eW2tP[t] = f2bf(eW2[korig(kp) * DIM + j]);
    } else if (i < 73728) {                // cW1t [128][128] (natural — m tile unpermuted)
        int t = i - 57344; int j = t >> 7, k = t & 127;
        cW1t[t] = f2bf(cW1[k * DIM + j]);
    } else if (i < 90112) {                // nW2t [128][128]
        int t = i - 73728; int j = t >> 7, k = t & 127;
        nW2t[t] = f2bf(nW2[k * DIM + j]);
    } else if (i < 102400) {               // tWe2 [128][96]: temb rows, dist row, zeros
        int t = i - 90112; int j = t / 96, k = t - j * 96;
        float v = (k < 64) ? eW1[(257 + k) * DIM + j]
                 : (k == 64) ? eW1[256 * DIM + j] : 0.f;
        tWe2[t] = f2bf(v);
    } else if (i < 118784) {               // eW1tS [128][128] rows 0..127
        int t = i - 102400; int j = t >> 7, k = t & 127;
        eW1tS[t] = f2bf(eW1[k * DIM + j]);
    } else if (i < 135168) {               // eW1tD [128][128] rows 128..255
        int t = i - 118784; int j = t >> 7, k = t & 127;
        eW1tD[t] = f2bf(eW1[(128 + k) * DIM + j]);
    }
}

// ---------------- K2: exclusive scan of deg ----------------
__global__ __launch_bounds__(256) void k_scan(const int* __restrict__ deg,
                                              int* __restrict__ offs, int* __restrict__ cursor){
    __shared__ int ps[256];
    int t = threadIdx.x;
    int base = t * 40, cnt = 0;
    if (t < 250) for (int i = 0; i < 40; ++i) cnt += deg[base + i];
    ps[t] = cnt; __syncthreads();
    for (int d = 1; d < 256; d <<= 1) {
        int v = (t >= d) ? ps[t - d] : 0;
        __syncthreads();
        ps[t] += v;
        __syncthreads();
    }
    int run = (t > 0) ? ps[t - 1] : 0;
    if (t < 250) for (int i = 0; i < 40; ++i) {
        offs[base + i] = run; cursor[base + i] = run; run += deg[base + i];
    }
    if (t == 0) offs[NN] = NE;
}

// ---------------- K3: H12p (paired u32) + packed payload scatter ----------------
// H12p[node][128] u32: idx [0,64) = src-half pairs (c, c+16) of h@W_src+b1;
//                      idx [64,128) = dst-half pairs of h@W_dst.
__global__ __launch_bounds__(256) void k_prep2(
    const float* __restrict__ h, const float* __restrict__ eb1,
    const u16* __restrict__ eW1tS, const u16* __restrict__ eW1tD,
    const int* __restrict__ esrc, const int* __restrict__ edst,
    const float* __restrict__ dist, const float* __restrict__ diffc,
    int* __restrict__ cursor,
    uint4* __restrict__ epack, float4* __restrict__ diff4,
    unsigned* __restrict__ H12p)
{
    __shared__ u16 Hbuf[64 * LDH];
    const int tid = threadIdx.x;

    if (blockIdx.x < 2500) {               // ---- scatter part: 2 × 16B per edge ----
        int i = blockIdx.x * 256 + tid;
        if (i < NE) {
            int d = edst[i];
            int pos = atomicAdd(&cursor[d], 1);
            union { float f; unsigned u; } dv; dv.f = dist[i];
            epack[pos] = make_uint4((unsigned)esrc[i], (unsigned)d, dv.u, (unsigned)i);
            diff4[pos] = make_float4(diffc[(size_t)i * 3 + 0],
                                     diffc[(size_t)i * 3 + 1],
                                     diffc[(size_t)i * 3 + 2], 0.f);
        }
        return;
    }

    // ---- H12 part: 157 blocks, 64 nodes each ----
    const int lane = tid & 63, w = tid >> 6;
    const int lo = lane & 15, hi = lane >> 4;
    const int nbase = (blockIdx.x - 2500) * 64;

    #pragma unroll
    for (int it = 0; it < 8; ++it) {
        int f = it * 256 + tid, e = f >> 5, c = f & 31;
        int node = nbase + e; if (node >= NN) node = NN - 1;
        float4 v = *reinterpret_cast<const float4*>(h + (size_t)node * DIM + c * 4);
        unsigned p0 = f2bf2(v.x, v.y), p1 = f2bf2(v.z, v.w);
        *reinterpret_cast<uint2*>(&Hbuf[e * LDH + c * 4]) = make_uint2(p0, p1);
    }
    __syncthreads();

    const u16* Wt = (w < 2) ? eW1tS : eW1tD;
    const int cc = (w & 1) * 64;
    f32x4 acc[4][4];
    #pragma unroll
    for (int rt = 0; rt < 4; ++rt)
        #pragma unroll
        for (int n = 0; n < 4; ++n) acc[rt][n] = f32x4{0.f,0.f,0.f,0.f};
    for (int ks = 0; ks < 4; ++ks) {
        bf16x8 a[4], b[4];
        #pragma unroll
        for (int rt = 0; rt < 4; ++rt)
            a[rt] = *reinterpret_cast<const bf16x8*>(&Hbuf[(rt*16+lo)*LDH + ks*32 + hi*8]);
        #pragma unroll
        for (int n = 0; n < 4; ++n)
            b[n] = *reinterpret_cast<const bf16x8*>(&Wt[(cc + n*16 + lo)*128 + ks*32 + hi*8]);
        #pragma unroll
        for (int rt = 0; rt < 4; ++rt)
            #pragma unroll
            for (int n = 0; n < 4; ++n)
                acc[rt][n] = __builtin_amdgcn_mfma_f32_16x16x32_bf16(a[rt], b[n], acc[rt][n], 0, 0, 0);
    }
    // paired u32 writes: (col c, c+16) from (n, n+1), n in {0, 2}
    const int base = (w < 2) ? 0 : 64;
    #pragma unroll
    for (int n = 0; n < 4; n += 2) {
        int c0 = cc + n * 16 + lo;                     // orig col (low member)
        int u32i = (cc >> 1) + ((n >> 1) << 4) + lo;   // pair index within half
        float b0 = (w < 2) ? eb1[c0] : 0.f;
        float b1 = (w < 2) ? eb1[c0 + 16] : 0.f;
        #pragma unroll
        for (int rt = 0; rt < 4; ++rt)
            #pragma unroll
            for (int r = 0; r < 4; ++r) {
                int node = nbase + rt * 16 + hi * 4 + r;
                if (node < NN)
                    H12p[(size_t)node * 128 + base + u32i] =
                        f2bf2(acc[rt][n][r] + b0, acc[rt][n + 1][r] + b1);
            }
    }
}

// ---------------- edge kernel: 64 dst-sorted edges/block, 4 waves, 6 blocks/CU ----------------
__global__ __launch_bounds__(256, 6) void egnn_edge10(
    const uint4* __restrict__ epack, const float4* __restrict__ diff4,
    const float* __restrict__ tembE,
    const float* __restrict__ eb2, const float* __restrict__ cb1,
    const float* __restrict__ cW2,
    const unsigned* __restrict__ H12p, const u16* __restrict__ tWe2,
    const u16* __restrict__ eW2tP, const u16* __restrict__ cW1t,
    float* __restrict__ m_i, float* __restrict__ coord_out)
{
    __shared__ u16 B[64 * LDX];     // reused: Tbuf[64][LDT2] -> x1(pair-permuted) -> m(natural)
    __shared__ int seid[64], srcv[64], dstv[64], flags[64];
    __shared__ float cwpart[4][64];

    const int tid = threadIdx.x, lane = tid & 63, w = tid >> 6;
    const int lo = lane & 15, hi = lane >> 4;
    const int bid = (blockIdx.x & 7) * 1250 + (blockIdx.x >> 3);   // XCD swizzle
    const int ebase = bid * 64;
    const int colb = w * 32;
    const int col0 = colb + lo;

    float dl = 0.f;
    if (tid < 64) {
        uint4 ep = epack[ebase + tid];
        srcv[tid] = (int)ep.x;
        dstv[tid] = (int)ep.y;
        union { unsigned u; float f; } dv; dv.u = ep.z;
        dl = dv.f;
        seid[tid] = (int)ep.w;
    }
    __syncthreads();

    if (tid < 64) {
        flags[tid] = (tid == 63) || (dstv[tid] != dstv[tid + 1]);
        uint4 z0 = make_uint4((unsigned)f2bf(dl), 0u, 0u, 0u);
        uint4 zz = make_uint4(0u, 0u, 0u, 0u);
        *reinterpret_cast<uint4*>(&B[tid * LDT2 + 64]) = z0;
        *reinterpret_cast<uint4*>(&B[tid * LDT2 + 72]) = zz;
        *reinterpret_cast<uint4*>(&B[tid * LDT2 + 80]) = zz;
        *reinterpret_cast<uint4*>(&B[tid * LDT2 + 88]) = zz;
    }
    #pragma unroll
    for (int it = 0; it < 4; ++it) {
        int f = it * 256 + tid, e = f >> 4, c = f & 15;
        float4 v = *reinterpret_cast<const float4*>(tembE + (size_t)seid[e] * TD + c * 4);
        unsigned p0 = f2bf2(v.x, v.y), p1 = f2bf2(v.z, v.w);
        *reinterpret_cast<uint2*>(&B[e * LDT2 + c * 4]) = make_uint2(p0, p1);
    }
    __syncthreads();

    f32x4 acc[4][2];
    // ---- GEMM1: [64x96] @ tWe2 -> x1 partial (temb + dist*w1d) ----
    #pragma unroll
    for (int rt = 0; rt < 4; ++rt)
        #pragma unroll
        for (int n = 0; n < 2; ++n) acc[rt][n] = f32x4{0.f,0.f,0.f,0.f};
    #pragma unroll
    for (int ks = 0; ks < 3; ++ks) {
        bf16x8 a[4], b[2];
        #pragma unroll
        for (int rt = 0; rt < 4; ++rt)
            a[rt] = *reinterpret_cast<const bf16x8*>(&B[(rt*16+lo)*LDT2 + ks*32 + hi*8]);
        #pragma unroll
        for (int n = 0; n < 2; ++n)
            b[n] = *reinterpret_cast<const bf16x8*>(&tWe2[(colb + n*16 + lo)*96 + ks*32 + hi*8]);
        #pragma unroll
        for (int rt = 0; rt < 4; ++rt)
            #pragma unroll
            for (int n = 0; n < 2; ++n)
                acc[rt][n] = __builtin_amdgcn_mfma_f32_16x16x32_bf16(a[rt], b[n], acc[rt][n], 0, 0, 0);
    }
    __syncthreads();   // Tbuf fully consumed (B about to be overwritten as x1)

    // ---- FUSED epilogue 1 (fragment space): x1 = silu(acc + H12p[src] + H12p[dst])
    //      one packed u32 write per (rt,r); LDS x1 layout = pair-permuted (matches eW2tP).
    {
        const int u32i = (colb >> 1) + lo;    // pair index for (col0, col0+16)
        #pragma unroll
        for (int rt = 0; rt < 4; ++rt)
            #pragma unroll
            for (int r = 0; r < 4; ++r) {
                int row = rt * 16 + hi * 4 + r;
                unsigned us = H12p[(size_t)srcv[row] * 128 + u32i];
                unsigned ud = H12p[(size_t)dstv[row] * 128 + 64 + u32i];
                float x0 = acc[rt][0][r] + bfu2f(us & 0xffffu) + bfu2f(ud & 0xffffu);
                float x1 = acc[rt][1][r] + bfu2f(us >> 16)     + bfu2f(ud >> 16);
                *reinterpret_cast<unsigned*>(&B[row * LDX + colb + lo * 2])
                    = f2bf2(silu_f(x0), silu_f(x1));
            }
    }
    __syncthreads();

    // ---- GEMM2: silu(x1) @ eW2tP (K rows match pair-permuted x1) ----
    #pragma unroll
    for (int rt = 0; rt < 4; ++rt)
        #pragma unroll
        for (int n = 0; n < 2; ++n) acc[rt][n] = f32x4{0.f,0.f,0.f,0.f};
    #pragma unroll
    for (int ks = 0; ks < 4; ++ks) {
        bf16x8 a[4], b[2];
        #pragma unroll
        for (int rt = 0; rt < 4; ++rt)
            a[rt] = *reinterpret_cast<const bf16x8*>(&B[(rt*16+lo)*LDX + ks*32 + hi*8]);
        #pragma unroll
        for (int n = 0; n < 2; ++n)
            b[n] = *reinterpret_cast<const bf16x8*>(&eW2tP[(colb + n*16 + lo)*128 + ks*32 + hi*8]);
        #pragma unroll
        for (int rt = 0; rt < 4; ++rt)
            #pragma unroll
            for (int n = 0; n < 2; ++n)
                acc[rt][n] = __builtin_amdgcn_mfma_f32_16x16x32_bf16(a[rt], b[n], acc[rt][n], 0, 0, 0);
    }
    __syncthreads();   // B(x1) fully consumed

    // ---- epilogue 2: m = silu(. + eb2) -> B (NATURAL layout, unchanged) ----
    {
        float b20 = eb2[col0], b21 = eb2[col0 + 16];
        #pragma unroll
        for (int rt = 0; rt < 4; ++rt)
            #pragma unroll
            for (int r = 0; r < 4; ++r) {
                int row = rt * 16 + hi * 4 + r;
                unsigned p = f2bf2(silu_f(acc[rt][0][r] + b20), silu_f(acc[rt][1][r] + b21));
                B[row * LDX + col0]      = (u16)p;
                B[row * LDX + col0 + 16] = (u16)(p >> 16);
            }
    }
    __syncthreads();

    // ---- GEMM3: m @ cW1t + cb1, SiLU, dot cW2 -> coord_w partials ----
    #pragma unroll
    for (int rt = 0; rt < 4; ++rt)
        #pragma unroll
        for (int n = 0; n < 2; ++n) acc[rt][n] = f32x4{0.f,0.f,0.f,0.f};
    #pragma unroll
    for (int ks = 0; ks < 4; ++ks) {
        bf16x8 a[4], b[2];
        #pragma unroll
        for (int rt = 0; rt < 4; ++rt)
            a[rt] = *reinterpret_cast<const bf16x8*>(&B[(rt*16+lo)*LDX + ks*32 + hi*8]);
        #pragma unroll
        for (int n = 0; n < 2; ++n)
            b[n] = *reinterpret_cast<const bf16x8*>(&cW1t[(colb + n*16 + lo)*128 + ks*32 + hi*8]);
        #pragma unroll
        for (int rt = 0; rt < 4; ++rt)
            #pragma unroll
            for (int n = 0; n < 2; ++n)
                acc[rt][n] = __builtin_amdgcn_mfma_f32_16x16x32_bf16(a[rt], b[n], acc[rt][n], 0, 0, 0);
    }
    {
        float b30 = cb1[col0], b31 = cb1[col0 + 16];
        float c20 = cW2[col0], c21 = cW2[col0 + 16];
        #pragma unroll
        for (int rt = 0; rt < 4; ++rt)
            #pragma unroll
            for (int r = 0; r < 4; ++r) {
                float p = silu_f(acc[rt][0][r] + b30) * c20
                        + silu_f(acc[rt][1][r] + b31) * c21;
                p += __shfl_xor(p, 1, 16);
                p += __shfl_xor(p, 2, 16);
                p += __shfl_xor(p, 4, 16);
                p += __shfl_xor(p, 8, 16);
                if (lo == 0) cwpart[w][rt * 16 + hi * 4 + r] = p;
            }
    }

    // ---- segmented column-sum of B (m, natural) -> m_i atomics (paired cols) ----
    {
        int cp = (tid & 63) * 2, rh = tid >> 6;         // 4 row-groups of 16
        float s0 = 0.f, s1 = 0.f;
        #pragma unroll
        for (int r = 0; r < 16; ++r) {
            int row = rh * 16 + r;
            unsigned u = *reinterpret_cast<const unsigned*>(&B[row * LDX + cp]);
            s0 += bfu2f(u & 0xffffu); s1 += bfu2f(u >> 16);
            if (flags[row]) {
                unsafeAtomicAdd(&m_i[(size_t)dstv[row] * DIM + cp],     s0);
                unsafeAtomicAdd(&m_i[(size_t)dstv[row] * DIM + cp + 1], s1);
                s0 = 0.f; s1 = 0.f;
            }
        }
        if (s0 != 0.f || s1 != 0.f) {   // residual: segment spans the group boundary
            int lr = rh * 16 + 15;
            unsafeAtomicAdd(&m_i[(size_t)dstv[lr] * DIM + cp],     s0);
            unsafeAtomicAdd(&m_i[(size_t)dstv[lr] * DIM + cp + 1], s1);
        }
    }
    __syncthreads();

    // ---- coord scatter: 3 atomics per edge ----
    if (tid < 192) {
        int e = tid / 3, c = tid - e * 3;
        float cw = cwpart[0][e] + cwpart[1][e] + cwpart[2][e] + cwpart[3][e];
        float val = reinterpret_cast<const float*>(diff4 + (size_t)(ebase + e))[c] * cw;
        unsafeAtomicAdd(coord_out + (size_t)srcv[e] * 3 + c, val);
    }
}

// ---------------- node kernel: 64 nodes/block ----------------
__global__ __launch_bounds__(256) void egnn_node(
    const float* __restrict__ h, const float* __restrict__ m_i,
    const float* __restrict__ tembN,
    const float* __restrict__ nb1, const float* __restrict__ nb2,
    const u16* __restrict__ nW1t, const u16* __restrict__ nW2t,
    float* __restrict__ out)
{
    __shared__ u16 Abuf[64 * 328];
    __shared__ u16 Xbuf[64 * LDX];

    const int tid = threadIdx.x, lane = tid & 63, w = tid >> 6;
    const int lo = lane & 15, hi = lane >> 4;
    const int nbase = blockIdx.x * 64;

    #pragma unroll
    for (int it = 0; it < 8; ++it) {
        int f = it * 256 + tid, e = f >> 5, c = f & 31;
        int node = nbase + e; if (node >= NN) node = NN - 1;
        float4 v = *reinterpret_cast<const float4*>(h + (size_t)node * DIM + c * 4);
        unsigned p0 = f2bf2(v.x, v.y), p1 = f2bf2(v.z, v.w);
        *reinterpret_cast<uint2*>(&Abuf[e * 328 + c * 4]) = make_uint2(p0, p1);
        float4 v2 = *reinterpret_cast<const float4*>(m_i + (size_t)node * DIM + c * 4);
        unsigned q0 = f2bf2(v2.x, v2.y), q1 = f2bf2(v2.z, v2.w);
        *reinterpret_cast<uint2*>(&Abuf[e * 328 + 128 + c * 4]) = make_uint2(q0, q1);
    }
    #pragma unroll
    for (int it = 0; it < 4; ++it) {
        int f = it * 256 + tid, e = f >> 4, c = f & 15;
        int node = nbase + e; if (node >= NN) node = NN - 1;
        float4 v = *reinterpret_cast<const float4*>(tembN + (size_t)node * TD + c * 4);
        unsigned p0 = f2bf2(v.x, v.y), p1 = f2bf2(v.z, v.w);
        *reinterpret_cast<uint2*>(&Abuf[e * 328 + 256 + c * 4]) = make_uint2(p0, p1);
    }
    __syncthreads();

    const int colb = w * 32;
    f32x4 acc[4][2];

    #pragma unroll
    for (int rt = 0; rt < 4; ++rt)
        #pragma unroll
        for (int n = 0; n < 2; ++n) acc[rt][n] = f32x4{0.f,0.f,0.f,0.f};
    for (int ks = 0; ks < 10; ++ks) {
        bf16x8 a[4], b[2];
        #pragma unroll
        for (int rt = 0; rt < 4; ++rt)
            a[rt] = *reinterpret_cast<const bf16x8*>(&Abuf[(rt*16+lo)*328 + ks*32 + hi*8]);
        #pragma unroll
        for (int n = 0; n < 2; ++n)
            b[n] = *reinterpret_cast<const bf16x8*>(&nW1t[(colb + n*16 + lo)*320 + ks*32 + hi*8]);
        #pragma unroll
        for (int rt = 0; rt < 4; ++rt)
            #pragma unroll
            for (int n = 0; n < 2; ++n)
                acc[rt][n] = __builtin_amdgcn_mfma_f32_16x16x32_bf16(a[rt], b[n], acc[rt][n], 0, 0, 0);
    }
    {
        float bias1[2];
        #pragma unroll
        for (int n = 0; n < 2; ++n) bias1[n] = nb1[colb + n*16 + lo];
        #pragma unroll
        for (int rt = 0; rt < 4; ++rt)
            #pragma unroll
            for (int n = 0; n < 2; ++n)
                #pragma unroll
                for (int r = 0; r < 4; ++r) {
                    int row = rt * 16 + hi * 4 + r;
                    Xbuf[row * LDX + colb + n*16 + lo] = f2bf(silu_f(acc[rt][n][r] + bias1[n]));
                }
    }
    __syncthreads();

    #pragma unroll
    for (int rt = 0; rt < 4; ++rt)
        #pragma unroll
        for (int n = 0; n < 2; ++n) acc[rt][n] = f32x4{0.f,0.f,0.f,0.f};
    #pragma unroll
    for (int ks = 0; ks < 4; ++ks) {
        bf16x8 a[4], b[2];
        #pragma unroll
        for (int rt = 0; rt < 4; ++rt)
            a[rt] = *reinterpret_cast<const bf16x8*>(&Xbuf[(rt*16+lo)*LDX + ks*32 + hi*8]);
        #pragma unroll
        for (int n = 0; n < 2; ++n)
            b[n] = *reinterpret_cast<const bf16x8*>(&nW2t[(colb + n*16 + lo)*128 + ks*32 + hi*8]);
        #pragma unroll
        for (int rt = 0; rt < 4; ++rt)
            #pragma unroll
            for (int n = 0; n < 2; ++n)
                acc[rt][n] = __builtin_amdgcn_mfma_f32_16x16x32_bf16(a[rt], b[n], acc[rt][n], 0, 0, 0);
    }
    {
        float bias2[2];
        #pragma unroll
        for (int n = 0; n < 2; ++n) bias2[n] = nb2[colb + n*16 + lo];
        #pragma unroll
        for (int rt = 0; rt < 4; ++rt)
            #pragma unroll
            for (int n = 0; n < 2; ++n)
                #pragma unroll
                for (int r = 0; r < 4; ++r) {
                    int row = rt * 16 + hi * 4 + r;
                    int node = nbase + row;
                    if (node < NN) {
                        int col = colb + n * 16 + lo;
                        out[(size_t)node * DIM + col] =
                            acc[rt][n][r] + bias2[n] + h[(size_t)node * DIM + col];
                    }
                }
    }
}

extern "C" void kernel_launch(void* const* d_in, const int* in_sizes, int n_in,
                              void* d_out, int out_size, void* d_ws, size_t ws_size,
                              hipStream_t stream)
{
    const float* h     = (const float*)d_in[0];
    const float* diffc = (const float*)d_in[1];
    const float* dist  = (const float*)d_in[2];
    const int*   esrc  = (const int*)d_in[3];
    const int*   edst  = (const int*)d_in[4];
    const float* tembE = (const float*)d_in[5];
    const float* tembN = (const float*)d_in[6];
    const float* eW1   = (const float*)d_in[7];
    const float* eb1   = (const float*)d_in[8];
    const float* eW2   = (const float*)d_in[9];
    const float* eb2   = (const float*)d_in[10];
    const float* cW1   = (const float*)d_in[11];
    const float* cb1   = (const float*)d_in[12];
    const float* cW2   = (const float*)d_in[13];
    const float* nW1   = (const float*)d_in[14];
    const float* nb1   = (const float*)d_in[15];
    const float* nW2   = (const float*)d_in[16];
    const float* nb2   = (const float*)d_in[17];

    char* ws = (char*)d_ws;
    unsigned* H12p = (unsigned*)(ws + 0);           //  5,120,000 (NN*128 u32)
    float* m_i    = (float*)(ws + 5120000);         //  5,120,000
    u16*   tWe2   = (u16*)(ws + 10240000);          //     24,576
    u16*   eW1tS  = (u16*)(ws + 10264576);          //     32,768
    u16*   eW1tD  = (u16*)(ws + 10297344);          //     32,768
    u16*   eW2tP  = (u16*)(ws + 10330112);          //     32,768
    u16*   cW1t   = (u16*)(ws + 10362880);          //     32,768
    u16*   nW1t   = (u16*)(ws + 10395648);          //     81,920
    u16*   nW2t   = (u16*)(ws + 10477568);          //     32,768
    int*   deg    = (int*)(ws + 10510336);          //     40,064
    int*   offs   = (int*)(ws + 10550400);          //     40,064
    int*   cursor = (int*)(ws + 10590464);          //     40,064
    uint4* epack  = (uint4*)(ws + 10630528);        // 10,240,000 (16B aligned)
    float4* diff4 = (float4*)(ws + 20870528);       // 10,240,000 -> 31,110,528 total

    float* outp      = (float*)d_out;
    float* coord_out = outp + (size_t)NN * DIM;

    // h-region of out fully overwritten by egnn_node; coord_out/m_i zeroed in k_prep1.
    hipMemsetAsync(deg, 0, 40064, stream);

    k_prep1<<<2500, 256, 0, stream>>>(eW1, nW1, eW2, cW1, nW2, edst,
                                      nW1t, eW2tP, cW1t, nW2t, tWe2, eW1tS, eW1tD,
                                      deg, m_i, coord_out);
    k_scan<<<1, 256, 0, stream>>>(deg, offs, cursor);
    k_prep2<<<2500 + (NN + 63) / 64, 256, 0, stream>>>(h, eb1, eW1tS, eW1tD,
                                                       esrc, edst, dist, diffc,
                                                       cursor, epack, diff4, H12p);
    egnn_edge10<<<NE / 64, 256, 0, stream>>>(epack, diff4, tembE, eb2, cb1, cW2,
                                             H12p, tWe2, eW2tP, cW1t, m_i, coord_out);
    egnn_node<<<(NN + 63) / 64, 256, 0, stream>>>(h, m_i, tembN, nb1, nb2,
                                                  nW1t, nW2t, outp);
}

// Round 13
// 272.536 us; speedup vs baseline: 1.1374x; 1.1374x over previous
//
#include <hip/hip_runtime.h>

typedef __bf16 bf16x8 __attribute__((ext_vector_type(8)));
typedef float f32x4 __attribute__((ext_vector_type(4)));
typedef unsigned short u16;

#define NN 10000
#define NE 640000
#define DIM 128
#define TD 64
#define LDT2 112  // 96-col Tbuf stride (bf16 elems): temb(64) + dist(1) + zeros
#define LDX 136   // 128-col tile stride (bf16 elems)
#define LDH 136

__device__ __forceinline__ u16 f2bf(float f){
    union { float f; unsigned u; } v; v.f = f;
    unsigned r = v.u + 0x7fffu + ((v.u >> 16) & 1u);
    return (u16)(r >> 16);
}
__device__ __forceinline__ unsigned f2bf2(float a, float b){   // low=a, high=b, RNE
    unsigned r;
    asm("v_cvt_pk_bf16_f32 %0, %1, %2" : "=v"(r) : "v"(a), "v"(b));
    return r;
}
__device__ __forceinline__ float bfu2f(unsigned hs){
    union { unsigned u; float f; } v; v.u = hs << 16; return v.f;
}
// silu via v_rcp_f32: avoids the ~10-instr IEEE f32 division sequence.
// rcp rel-err ~1ulp f32, far below the bf16 rounding already applied downstream.
__device__ __forceinline__ float silu_f(float x){
    float d = 1.0f + __expf(-x);
    float r;
    asm("v_rcp_f32 %0, %1" : "=v"(r) : "v"(d));
    return x * r;
}

__device__ __forceinline__ unsigned silu_add3_pk(unsigned xb, unsigned us, unsigned ud){
    float a0 = bfu2f(xb & 0xffffu) + bfu2f(us & 0xffffu) + bfu2f(ud & 0xffffu);
    float a1 = bfu2f(xb >> 16)     + bfu2f(us >> 16)     + bfu2f(ud >> 16);
    return f2bf2(silu_f(a0), silu_f(a1));
}

// ---------------- K1: weight prep + dst histogram + zero m_i/coord ----------------
__global__ __launch_bounds__(256) void k_prep1(
    const float* __restrict__ eW1, const float* __restrict__ nW1,
    const float* __restrict__ eW2, const float* __restrict__ cW1,
    const float* __restrict__ nW2, const int* __restrict__ edst,
    u16* __restrict__ nW1t, u16* __restrict__ eW2t, u16* __restrict__ cW1t,
    u16* __restrict__ nW2t, u16* __restrict__ tWe2,
    u16* __restrict__ eW1tS, u16* __restrict__ eW1tD,
    int* __restrict__ deg, float* __restrict__ m_i, float* __restrict__ coord_out)
{
    int i = blockIdx.x * 256 + threadIdx.x;     // grid: 2500 blocks = 640000 threads
    if (i < NE) {
        atomicAdd(&deg[edst[i]], 1);
        *reinterpret_cast<float2*>(m_i + (size_t)i * 2) = make_float2(0.f, 0.f);
    }
    if (i < NN * 3) coord_out[i] = 0.f;

    if (i < 40960) {                       // nW1t [128][320]
        int j = i / 320, k = i - j * 320;
        nW1t[i] = f2bf(nW1[k * DIM + j]);
    } else if (i < 57344) {                // eW2t [128][128]
        int t = i - 40960; int j = t >> 7, k = t & 127;
        eW2t[t] = f2bf(eW2[k * DIM + j]);
    } else if (i < 73728) {                // cW1t [128][128]
        int t = i - 57344; int j = t >> 7, k = t & 127;
        cW1t[t] = f2bf(cW1[k * DIM + j]);
    } else if (i < 90112) {                // nW2t [128][128]
        int t = i - 73728; int j = t >> 7, k = t & 127;
        nW2t[t] = f2bf(nW2[k * DIM + j]);
    } else if (i < 102400) {               // tWe2 [128][96]: temb rows, dist row, zeros
        int t = i - 90112; int j = t / 96, k = t - j * 96;
        float v = (k < 64) ? eW1[(257 + k) * DIM + j]
                 : (k == 64) ? eW1[256 * DIM + j] : 0.f;
        tWe2[t] = f2bf(v);
    } else if (i < 118784) {               // eW1tS [128][128] rows 0..127
        int t = i - 102400; int j = t >> 7, k = t & 127;
        eW1tS[t] = f2bf(eW1[k * DIM + j]);
    } else if (i < 135168) {               // eW1tD [128][128] rows 128..255
        int t = i - 118784; int j = t >> 7, k = t & 127;
        eW1tD[t] = f2bf(eW1[(128 + k) * DIM + j]);
    }
}

// ---------------- K2: exclusive scan of deg ----------------
__global__ __launch_bounds__(256) void k_scan(const int* __restrict__ deg,
                                              int* __restrict__ offs, int* __restrict__ cursor){
    __shared__ int ps[256];
    int t = threadIdx.x;
    int base = t * 40, cnt = 0;
    if (t < 250) for (int i = 0; i < 40; ++i) cnt += deg[base + i];
    ps[t] = cnt; __syncthreads();
    for (int d = 1; d < 256; d <<= 1) {
        int v = (t >= d) ? ps[t - d] : 0;
        __syncthreads();
        ps[t] += v;
        __syncthreads();
    }
    int run = (t > 0) ? ps[t - 1] : 0;
    if (t < 250) for (int i = 0; i < 40; ++i) {
        offs[base + i] = run; cursor[base + i] = run; run += deg[base + i];
    }
    if (t == 0) offs[NN] = NE;
}

// ---------------- K3: H12 + packed payload scatter ----------------
__global__ __launch_bounds__(256) void k_prep2(
    const float* __restrict__ h, const float* __restrict__ eb1,
    const u16* __restrict__ eW1tS, const u16* __restrict__ eW1tD,
    const int* __restrict__ esrc, const int* __restrict__ edst,
    const float* __restrict__ dist, const float* __restrict__ diffc,
    int* __restrict__ cursor,
    uint4* __restrict__ epack, float4* __restrict__ diff4,
    u16* __restrict__ H12)
{
    __shared__ u16 Hbuf[64 * LDH];
    const int tid = threadIdx.x;

    if (blockIdx.x < 2500) {               // ---- scatter part: 2 × 16B per edge ----
        int i = blockIdx.x * 256 + tid;
        if (i < NE) {
            int d = edst[i];
            int pos = atomicAdd(&cursor[d], 1);
            union { float f; unsigned u; } dv; dv.f = dist[i];
            epack[pos] = make_uint4((unsigned)esrc[i], (unsigned)d, dv.u, (unsigned)i);
            diff4[pos] = make_float4(diffc[(size_t)i * 3 + 0],
                                     diffc[(size_t)i * 3 + 1],
                                     diffc[(size_t)i * 3 + 2], 0.f);
        }
        return;
    }

    // ---- H12 part: 157 blocks, 64 nodes each ----
    const int lane = tid & 63, w = tid >> 6;
    const int lo = lane & 15, hi = lane >> 4;
    const int nbase = (blockIdx.x - 2500) * 64;

    #pragma unroll
    for (int it = 0; it < 8; ++it) {
        int f = it * 256 + tid, e = f >> 5, c = f & 31;
        int node = nbase + e; if (node >= NN) node = NN - 1;
        float4 v = *reinterpret_cast<const float4*>(h + (size_t)node * DIM + c * 4);
        unsigned p0 = f2bf2(v.x, v.y), p1 = f2bf2(v.z, v.w);
        *reinterpret_cast<uint2*>(&Hbuf[e * LDH + c * 4]) = make_uint2(p0, p1);
    }
    __syncthreads();

    const u16* Wt = (w < 2) ? eW1tS : eW1tD;
    const int cc = (w & 1) * 64;
    f32x4 acc[4][4];
    #pragma unroll
    for (int rt = 0; rt < 4; ++rt)
        #pragma unroll
        for (int n = 0; n < 4; ++n) acc[rt][n] = f32x4{0.f,0.f,0.f,0.f};
    for (int ks = 0; ks < 4; ++ks) {
        bf16x8 a[4], b[4];
        #pragma unroll
        for (int rt = 0; rt < 4; ++rt)
            a[rt] = *reinterpret_cast<const bf16x8*>(&Hbuf[(rt*16+lo)*LDH + ks*32 + hi*8]);
        #pragma unroll
        for (int n = 0; n < 4; ++n)
            b[n] = *reinterpret_cast<const bf16x8*>(&Wt[(cc + n*16 + lo)*128 + ks*32 + hi*8]);
        #pragma unroll
        for (int rt = 0; rt < 4; ++rt)
            #pragma unroll
            for (int n = 0; n < 4; ++n)
                acc[rt][n] = __builtin_amdgcn_mfma_f32_16x16x32_bf16(a[rt], b[n], acc[rt][n], 0, 0, 0);
    }
    #pragma unroll
    for (int n = 0; n < 4; ++n) {
        int jloc = cc + n * 16 + lo;
        int j = ((w < 2) ? 0 : 128) + jloc;
        float bias = (w < 2) ? eb1[jloc] : 0.f;
        #pragma unroll
        for (int rt = 0; rt < 4; ++rt)
            #pragma unroll
            for (int r = 0; r < 4; ++r) {
                int node = nbase + rt * 16 + hi * 4 + r;
                if (node < NN) H12[(size_t)node * 256 + j] = f2bf(acc[rt][n][r] + bias);
            }
    }
}

// ---------------- edge kernel: 64 dst-sorted edges/block, 4 waves, 6 blocks/CU ----------------
__global__ __launch_bounds__(256, 6) void egnn_edge11(
    const uint4* __restrict__ epack, const float4* __restrict__ diff4,
    const float* __restrict__ tembE,
    const float* __restrict__ eb2, const float* __restrict__ cb1,
    const float* __restrict__ cW2,
    const u16* __restrict__ H12, const u16* __restrict__ tWe2,
    const u16* __restrict__ eW2t, const u16* __restrict__ cW1t,
    float* __restrict__ m_i, float* __restrict__ coord_out)
{
    __shared__ u16 B[64 * LDX];     // reused: Tbuf[64][LDT2] -> x1 -> m
    __shared__ int seid[64], srcv[64], dstv[64], flags[64];
    __shared__ float cwpart[4][64];

    const int tid = threadIdx.x, lane = tid & 63, w = tid >> 6;
    const int lo = lane & 15, hi = lane >> 4;
    const int bid = (blockIdx.x & 7) * 1250 + (blockIdx.x >> 3);   // XCD swizzle
    const int ebase = bid * 64;
    const int colb = w * 32;
    const int col0 = colb + lo;

    float dl = 0.f;
    if (tid < 64) {
        uint4 ep = epack[ebase + tid];
        srcv[tid] = (int)ep.x;
        dstv[tid] = (int)ep.y;
        union { unsigned u; float f; } dv; dv.u = ep.z;
        dl = dv.f;
        seid[tid] = (int)ep.w;
    }
    __syncthreads();

    if (tid < 64) {
        flags[tid] = (tid == 63) || (dstv[tid] != dstv[tid + 1]);
        uint4 z0 = make_uint4((unsigned)f2bf(dl), 0u, 0u, 0u);
        uint4 zz = make_uint4(0u, 0u, 0u, 0u);
        *reinterpret_cast<uint4*>(&B[tid * LDT2 + 64]) = z0;
        *reinterpret_cast<uint4*>(&B[tid * LDT2 + 72]) = zz;
        *reinterpret_cast<uint4*>(&B[tid * LDT2 + 80]) = zz;
        *reinterpret_cast<uint4*>(&B[tid * LDT2 + 88]) = zz;
    }
    #pragma unroll
    for (int it = 0; it < 4; ++it) {
        int f = it * 256 + tid, e = f >> 4, c = f & 15;
        float4 v = *reinterpret_cast<const float4*>(tembE + (size_t)seid[e] * TD + c * 4);
        unsigned p0 = f2bf2(v.x, v.y), p1 = f2bf2(v.z, v.w);
        *reinterpret_cast<uint2*>(&B[e * LDT2 + c * 4]) = make_uint2(p0, p1);
    }
    __syncthreads();

    f32x4 acc[4][2];
    // ---- GEMM1: [64x96] @ tWe2 -> x1 partial (temb + dist*w1d) ----
    #pragma unroll
    for (int rt = 0; rt < 4; ++rt)
        #pragma unroll
        for (int n = 0; n < 2; ++n) acc[rt][n] = f32x4{0.f,0.f,0.f,0.f};
    #pragma unroll
    for (int ks = 0; ks < 3; ++ks) {
        bf16x8 a[4], b[2];
        #pragma unroll
        for (int rt = 0; rt < 4; ++rt)
            a[rt] = *reinterpret_cast<const bf16x8*>(&B[(rt*16+lo)*LDT2 + ks*32 + hi*8]);
        #pragma unroll
        for (int n = 0; n < 2; ++n)
            b[n] = *reinterpret_cast<const bf16x8*>(&tWe2[(colb + n*16 + lo)*96 + ks*32 + hi*8]);
        #pragma unroll
        for (int rt = 0; rt < 4; ++rt)
            #pragma unroll
            for (int n = 0; n < 2; ++n)
                acc[rt][n] = __builtin_amdgcn_mfma_f32_16x16x32_bf16(a[rt], b[n], acc[rt][n], 0, 0, 0);
    }
    __syncthreads();   // Tbuf fully consumed

    // ---- write x1 partial (fragment space, bf16) -> B ----
    #pragma unroll
    for (int rt = 0; rt < 4; ++rt)
        #pragma unroll
        for (int n = 0; n < 2; ++n)
            #pragma unroll
            for (int r = 0; r < 4; ++r)
                B[(rt*16 + hi*4 + r) * LDX + colb + n*16 + lo] = f2bf(acc[rt][n][r]);
    __syncthreads();

    // ---- epilogue 1 (vectorized): x1 = silu(partial + H12[src] + H12[dst]) ----
    {
        int row = tid >> 2, q = tid & 3;
        int sv = srcv[row], dv = dstv[row];
        const uint4* hs = reinterpret_cast<const uint4*>(H12 + (size_t)sv * 256 + q * 32);
        const uint4* hd = reinterpret_cast<const uint4*>(H12 + (size_t)dv * 256 + 128 + q * 32);
        uint4* bp = reinterpret_cast<uint4*>(&B[row * LDX + q * 32]);
        #pragma unroll
        for (int c4 = 0; c4 < 4; ++c4) {
            uint4 xb = bp[c4];
            uint4 us = hs[c4];
            uint4 ud = hd[c4];
            uint4 o;
            o.x = silu_add3_pk(xb.x, us.x, ud.x);
            o.y = silu_add3_pk(xb.y, us.y, ud.y);
            o.z = silu_add3_pk(xb.z, us.z, ud.z);
            o.w = silu_add3_pk(xb.w, us.w, ud.w);
            bp[c4] = o;
        }
    }
    __syncthreads();

    // ---- GEMM2: silu(x1) @ eW2t ----
    #pragma unroll
    for (int rt = 0; rt < 4; ++rt)
        #pragma unroll
        for (int n = 0; n < 2; ++n) acc[rt][n] = f32x4{0.f,0.f,0.f,0.f};
    #pragma unroll
    for (int ks = 0; ks < 4; ++ks) {
        bf16x8 a[4], b[2];
        #pragma unroll
        for (int rt = 0; rt < 4; ++rt)
            a[rt] = *reinterpret_cast<const bf16x8*>(&B[(rt*16+lo)*LDX + ks*32 + hi*8]);
        #pragma unroll
        for (int n = 0; n < 2; ++n)
            b[n] = *reinterpret_cast<const bf16x8*>(&eW2t[(colb + n*16 + lo)*128 + ks*32 + hi*8]);
        #pragma unroll
        for (int rt = 0; rt < 4; ++rt)
            #pragma unroll
            for (int n = 0; n < 2; ++n)
                acc[rt][n] = __builtin_amdgcn_mfma_f32_16x16x32_bf16(a[rt], b[n], acc[rt][n], 0, 0, 0);
    }
    __syncthreads();   // B(x1) fully consumed

    // ---- epilogue 2: m = silu(. + eb2) -> B ----
    {
        float b20 = eb2[col0], b21 = eb2[col0 + 16];
        #pragma unroll
        for (int rt = 0; rt < 4; ++rt)
            #pragma unroll
            for (int r = 0; r < 4; ++r) {
                int row = rt * 16 + hi * 4 + r;
                unsigned p = f2bf2(silu_f(acc[rt][0][r] + b20), silu_f(acc[rt][1][r] + b21));
                B[row * LDX + col0]      = (u16)p;
                B[row * LDX + col0 + 16] = (u16)(p >> 16);
            }
    }
    __syncthreads();

    // ---- GEMM3: m @ cW1t + cb1, SiLU, dot cW2 -> coord_w partials ----
    #pragma unroll
    for (int rt = 0; rt < 4; ++rt)
        #pragma unroll
        for (int n = 0; n < 2; ++n) acc[rt][n] = f32x4{0.f,0.f,0.f,0.f};
    #pragma unroll
    for (int ks = 0; ks < 4; ++ks) {
        bf16x8 a[4], b[2];
        #pragma unroll
        for (int rt = 0; rt < 4; ++rt)
            a[rt] = *reinterpret_cast<const bf16x8*>(&B[(rt*16+lo)*LDX + ks*32 + hi*8]);
        #pragma unroll
        for (int n = 0; n < 2; ++n)
            b[n] = *reinterpret_cast<const bf16x8*>(&cW1t[(colb + n*16 + lo)*128 + ks*32 + hi*8]);
        #pragma unroll
        for (int rt = 0; rt < 4; ++rt)
            #pragma unroll
            for (int n = 0; n < 2; ++n)
                acc[rt][n] = __builtin_amdgcn_mfma_f32_16x16x32_bf16(a[rt], b[n], acc[rt][n], 0, 0, 0);
    }
    {
        float b30 = cb1[col0], b31 = cb1[col0 + 16];
        float c20 = cW2[col0], c21 = cW2[col0 + 16];
        #pragma unroll
        for (int rt = 0; rt < 4; ++rt)
            #pragma unroll
            for (int r = 0; r < 4; ++r) {
                float p = silu_f(acc[rt][0][r] + b30) * c20
                        + silu_f(acc[rt][1][r] + b31) * c21;
                p += __shfl_xor(p, 1, 16);
                p += __shfl_xor(p, 2, 16);
                p += __shfl_xor(p, 4, 16);
                p += __shfl_xor(p, 8, 16);
                if (lo == 0) cwpart[w][rt * 16 + hi * 4 + r] = p;
            }
    }

    // ---- segmented column-sum of B (m) -> m_i atomics (paired cols) ----
    {
        int cp = (tid & 63) * 2, rh = tid >> 6;         // 4 row-groups of 16
        float s0 = 0.f, s1 = 0.f;
        #pragma unroll
        for (int r = 0; r < 16; ++r) {
            int row = rh * 16 + r;
            unsigned u = *reinterpret_cast<const unsigned*>(&B[row * LDX + cp]);
            s0 += bfu2f(u & 0xffffu); s1 += bfu2f(u >> 16);
            if (flags[row]) {
                unsafeAtomicAdd(&m_i[(size_t)dstv[row] * DIM + cp],     s0);
                unsafeAtomicAdd(&m_i[(size_t)dstv[row] * DIM + cp + 1], s1);
                s0 = 0.f; s1 = 0.f;
            }
        }
        if (s0 != 0.f || s1 != 0.f) {   // residual: segment spans the group boundary
            int lr = rh * 16 + 15;
            unsafeAtomicAdd(&m_i[(size_t)dstv[lr] * DIM + cp],     s0);
            unsafeAtomicAdd(&m_i[(size_t)dstv[lr] * DIM + cp + 1], s1);
        }
    }
    __syncthreads();

    // ---- coord scatter: 3 atomics per edge ----
    if (tid < 192) {
        int e = tid / 3, c = tid - e * 3;
        float cw = cwpart[0][e] + cwpart[1][e] + cwpart[2][e] + cwpart[3][e];
        float val = reinterpret_cast<const float*>(diff4 + (size_t)(ebase + e))[c] * cw;
        unsafeAtomicAdd(coord_out + (size_t)srcv[e] * 3 + c, val);
    }
}

// ---------------- node kernel: 64 nodes/block ----------------
__global__ __launch_bounds__(256) void egnn_node(
    const float* __restrict__ h, const float* __restrict__ m_i,
    const float* __restrict__ tembN,
    const float* __restrict__ nb1, const float* __restrict__ nb2,
    const u16* __restrict__ nW1t, const u16* __restrict__ nW2t,
    float* __restrict__ out)
{
    __shared__ u16 Abuf[64 * 328];
    __shared__ u16 Xbuf[64 * LDX];

    const int tid = threadIdx.x, lane = tid & 63, w = tid >> 6;
    const int lo = lane & 15, hi = lane >> 4;
    const int nbase = blockIdx.x * 64;

    #pragma unroll
    for (int it = 0; it < 8; ++it) {
        int f = it * 256 + tid, e = f >> 5, c = f & 31;
        int node = nbase + e; if (node >= NN) node = NN - 1;
        float4 v = *reinterpret_cast<const float4*>(h + (size_t)node * DIM + c * 4);
        unsigned p0 = f2bf2(v.x, v.y), p1 = f2bf2(v.z, v.w);
        *reinterpret_cast<uint2*>(&Abuf[e * 328 + c * 4]) = make_uint2(p0, p1);
        float4 v2 = *reinterpret_cast<const float4*>(m_i + (size_t)node * DIM + c * 4);
        unsigned q0 = f2bf2(v2.x, v2.y), q1 = f2bf2(v2.z, v2.w);
        *reinterpret_cast<uint2*>(&Abuf[e * 328 + 128 + c * 4]) = make_uint2(q0, q1);
    }
    #pragma unroll
    for (int it = 0; it < 4; ++it) {
        int f = it * 256 + tid, e = f >> 4, c = f & 15;
        int node = nbase + e; if (node >= NN) node = NN - 1;
        float4 v = *reinterpret_cast<const float4*>(tembN + (size_t)node * TD + c * 4);
        unsigned p0 = f2bf2(v.x, v.y), p1 = f2bf2(v.z, v.w);
        *reinterpret_cast<uint2*>(&Abuf[e * 328 + 256 + c * 4]) = make_uint2(p0, p1);
    }
    __syncthreads();

    const int colb = w * 32;
    f32x4 acc[4][2];

    #pragma unroll
    for (int rt = 0; rt < 4; ++rt)
        #pragma unroll
        for (int n = 0; n < 2; ++n) acc[rt][n] = f32x4{0.f,0.f,0.f,0.f};
    for (int ks = 0; ks < 10; ++ks) {
        bf16x8 a[4], b[2];
        #pragma unroll
        for (int rt = 0; rt < 4; ++rt)
            a[rt] = *reinterpret_cast<const bf16x8*>(&Abuf[(rt*16+lo)*328 + ks*32 + hi*8]);
        #pragma unroll
        for (int n = 0; n < 2; ++n)
            b[n] = *reinterpret_cast<const bf16x8*>(&nW1t[(colb + n*16 + lo)*320 + ks*32 + hi*8]);
        #pragma unroll
        for (int rt = 0; rt < 4; ++rt)
            #pragma unroll
            for (int n = 0; n < 2; ++n)
                acc[rt][n] = __builtin_amdgcn_mfma_f32_16x16x32_bf16(a[rt], b[n], acc[rt][n], 0, 0, 0);
    }
    {
        float bias1[2];
        #pragma unroll
        for (int n = 0; n < 2; ++n) bias1[n] = nb1[colb + n*16 + lo];
        #pragma unroll
        for (int rt = 0; rt < 4; ++rt)
            #pragma unroll
            for (int n = 0; n < 2; ++n)
                #pragma unroll
                for (int r = 0; r < 4; ++r) {
                    int row = rt * 16 + hi * 4 + r;
                    Xbuf[row * LDX + colb + n*16 + lo] = f2bf(silu_f(acc[rt][n][r] + bias1[n]));
                }
    }
    __syncthreads();

    #pragma unroll
    for (int rt = 0; rt < 4; ++rt)
        #pragma unroll
        for (int n = 0; n < 2; ++n) acc[rt][n] = f32x4{0.f,0.f,0.f,0.f};
    #pragma unroll
    for (int ks = 0; ks < 4; ++ks) {
        bf16x8 a[4], b[2];
        #pragma unroll
        for (int rt = 0; rt < 4; ++rt)
            a[rt] = *reinterpret_cast<const bf16x8*>(&Xbuf[(rt*16+lo)*LDX + ks*32 + hi*8]);
        #pragma unroll
        for (int n = 0; n < 2; ++n)
            b[n] = *reinterpret_cast<const bf16x8*>(&nW2t[(colb + n*16 + lo)*128 + ks*32 + hi*8]);
        #pragma unroll
        for (int rt = 0; rt < 4; ++rt)
            #pragma unroll
            for (int n = 0; n < 2; ++n)
                acc[rt][n] = __builtin_amdgcn_mfma_f32_16x16x32_bf16(a[rt], b[n], acc[rt][n], 0, 0, 0);
    }
    {
        float bias2[2];
        #pragma unroll
        for (int n = 0; n < 2; ++n) bias2[n] = nb2[colb + n*16 + lo];
        #pragma unroll
        for (int rt = 0; rt < 4; ++rt)
            #pragma unroll
            for (int n = 0; n < 2; ++n)
                #pragma unroll
                for (int r = 0; r < 4; ++r) {
                    int row = rt * 16 + hi * 4 + r;
                    int node = nbase + row;
                    if (node < NN) {
                        int col = colb + n * 16 + lo;
                        out[(size_t)node * DIM + col] =
                            acc[rt][n][r] + bias2[n] + h[(size_t)node * DIM + col];
                    }
                }
    }
}

extern "C" void kernel_launch(void* const* d_in, const int* in_sizes, int n_in,
                              void* d_out, int out_size, void* d_ws, size_t ws_size,
                              hipStream_t stream)
{
    const float* h     = (const float*)d_in[0];
    const float* diffc = (const float*)d_in[1];
    const float* dist  = (const float*)d_in[2];
    const int*   esrc  = (const int*)d_in[3];
    const int*   edst  = (const int*)d_in[4];
    const float* tembE = (const float*)d_in[5];
    const float* tembN = (const float*)d_in[6];
    const float* eW1   = (const float*)d_in[7];
    const float* eb1   = (const float*)d_in[8];
    const float* eW2   = (const float*)d_in[9];
    const float* eb2   = (const float*)d_in[10];
    const float* cW1   = (const float*)d_in[11];
    const float* cb1   = (const float*)d_in[12];
    const float* cW2   = (const float*)d_in[13];
    const float* nW1   = (const float*)d_in[14];
    const float* nb1   = (const float*)d_in[15];
    const float* nW2   = (const float*)d_in[16];
    const float* nb2   = (const float*)d_in[17];

    char* ws = (char*)d_ws;
    u16*   H12    = (u16*)(ws + 0);                 //  5,120,000
    float* m_i    = (float*)(ws + 5120000);         //  5,120,000
    u16*   tWe2   = (u16*)(ws + 10240000);          //     24,576
    u16*   eW1tS  = (u16*)(ws + 10264576);          //     32,768
    u16*   eW1tD  = (u16*)(ws + 10297344);          //     32,768
    u16*   eW2t   = (u16*)(ws + 10330112);          //     32,768
    u16*   cW1t   = (u16*)(ws + 10362880);          //     32,768
    u16*   nW1t   = (u16*)(ws + 10395648);          //     81,920
    u16*   nW2t   = (u16*)(ws + 10477568);          //     32,768
    int*   deg    = (int*)(ws + 10510336);          //     40,064
    int*   offs   = (int*)(ws + 10550400);          //     40,064
    int*   cursor = (int*)(ws + 10590464);          //     40,064
    uint4* epack  = (uint4*)(ws + 10630528);        // 10,240,000 (16B aligned)
    float4* diff4 = (float4*)(ws + 20870528);       // 10,240,000 -> 31,110,528 total

    float* outp      = (float*)d_out;
    float* coord_out = outp + (size_t)NN * DIM;

    // h-region of out fully overwritten by egnn_node; coord_out/m_i zeroed in k_prep1.
    hipMemsetAsync(deg, 0, 40064, stream);

    k_prep1<<<2500, 256, 0, stream>>>(eW1, nW1, eW2, cW1, nW2, edst,
                                      nW1t, eW2t, cW1t, nW2t, tWe2, eW1tS, eW1tD,
                                      deg, m_i, coord_out);
    k_scan<<<1, 256, 0, stream>>>(deg, offs, cursor);
    k_prep2<<<2500 + (NN + 63) / 64, 256, 0, stream>>>(h, eb1, eW1tS, eW1tD,
                                                       esrc, edst, dist, diffc,
                                                       cursor, epack, diff4, H12);
    egnn_edge11<<<NE / 64, 256, 0, stream>>>(epack, diff4, tembE, eb2, cb1, cW2,
                                             H12, tWe2, eW2t, cW1t, m_i, coord_out);
    egnn_node<<<(NN + 63) / 64, 256, 0, stream>>>(h, m_i, tembN, nb1, nb2,
                                                  nW1t, nW2t, outp);
}